// Round 6
// baseline (310.428 us; speedup 1.0000x reference)
//
#include <hip/hip_runtime.h>
#include <stdint.h>

#define N_TOKENS 32768
#define N_CODES  8192
#define DIM      256
#define EPSF     1e-8f

typedef __bf16 bf16x8 __attribute__((ext_vector_type(8)));
typedef float  f32x4  __attribute__((ext_vector_type(4)));
typedef unsigned short ushort8 __attribute__((ext_vector_type(8)));

// ws layout: [bf16 codebook, FRAGMENT ORDER, 4MiB][cnorm f32 32KiB][hist 32KiB]
#define WS_CNORM_OFF  (4u*1024u*1024u)
#define WS_HIST_OFF   (WS_CNORM_OFF + N_CODES*4u)

// ---------------------------------------------------------------------------
// K1: codebooks fp32 -> bf16 in MFMA-FRAGMENT ORDER, ||c||^2, zero hist.
//  Fragment layout: group g = cc*4 + q (16 codes), within group:
//    byte offset = kc*1024 + lane*16,  lane = lq*16 + lr
//    holds code row (g*16 + lr), dims [kc*32 + lq*8, +8) as 8 bf16.
//  So in k_argmin, wave quarter q reads B-frag kc as ONE coalesced 1024B
//  wave-load: cbh + g*8192 + kc*1024 + lane*16. No LDS needed for B.
//  Grid: 512 blocks (one per group) x 256 thr; 2 elements/thread.
//  Reads: each 128B line covers (kc, lq0..3) x one row -> 4 lanes of the
//  same wave-iter -> fully consumed. Writes: consecutive tid -> consecutive
//  16B -> fully coalesced.
// ---------------------------------------------------------------------------
__global__ __launch_bounds__(256) void k_prep(const float* __restrict__ cbf,
                                              unsigned short* __restrict__ cbh,
                                              float* __restrict__ cnorm,
                                              int* __restrict__ hist) {
    const int g   = blockIdx.x;        // code group 0..511 (16 codes each)
    const int tid = threadIdx.x;
    if (g < 32) hist[g * 256 + tid] = 0;

    __shared__ float nrm[16];
    if (tid < 16) nrm[tid] = 0.f;
    __syncthreads();

    #pragma unroll
    for (int i = 0; i < 2; ++i) {
        const int e  = i * 256 + tid;          // 0..511
        const int kc = e >> 6;
        const int ln = e & 63;
        const int lq = ln >> 4, lr = ln & 15;
        const float* src = cbf + ((size_t)(g * 16 + lr)) * DIM + kc * 32 + lq * 8;
        const float4 v0 = ((const float4*)src)[0];
        const float4 v1 = ((const float4*)src)[1];

        ushort8 u;
        u[0] = __builtin_bit_cast(unsigned short, (__bf16)v0.x);
        u[1] = __builtin_bit_cast(unsigned short, (__bf16)v0.y);
        u[2] = __builtin_bit_cast(unsigned short, (__bf16)v0.z);
        u[3] = __builtin_bit_cast(unsigned short, (__bf16)v0.w);
        u[4] = __builtin_bit_cast(unsigned short, (__bf16)v1.x);
        u[5] = __builtin_bit_cast(unsigned short, (__bf16)v1.y);
        u[6] = __builtin_bit_cast(unsigned short, (__bf16)v1.z);
        u[7] = __builtin_bit_cast(unsigned short, (__bf16)v1.w);
        *(ushort8*)((char*)cbh + (size_t)g * 8192 + kc * 1024 + ln * 16) = u;

        const float p = v0.x*v0.x + v0.y*v0.y + v0.z*v0.z + v0.w*v0.w
                      + v1.x*v1.x + v1.y*v1.y + v1.z*v1.z + v1.w*v1.w;
        atomicAdd(&nrm[lr], p);
    }
    __syncthreads();
    if (tid < 16) cnorm[g * 16 + tid] = nrm[tid];
}

// ---------------------------------------------------------------------------
// K2: fused distance-matmul + argmax(x.c - cn/2) + quant epilogue, v11.
//  v11 vs v5b..v10: B path REBUILT. All LDS-staged variants (cooperative,
//  counted-vmcnt, phased, private, asm-ordered) landed 165-198us because the
//  B data path itself (DMA->LDS write + 64 ds_read_b128 + 4cy/read conflict,
//  ~1100 cyc/chunk) serialized against the 1242-cyc matrix pipe with only
//  2 waves/SIMD. Fix: k_prep stores the codebook in MFMA-fragment order, so
//  each wave loads B straight into VGPRs with 8 coalesced 1024B wave-loads
//  per chunk (global_load_dwordx4/lane, L2-resident stream). Main loop has
//  ZERO LDS traffic, ZERO barriers, ZERO global_load_lds: every load is a
//  register load, so the compiler's own counted vmcnt scheduling applies
//  (the in-order-retire trap of mixed DMA+scalar loads is gone).
//  cn is loaded before the b[] block each iteration (oldest -> its wait
//  doesn't drain the b stream). LDS only: A-stage overlay + reductions.
// ---------------------------------------------------------------------------
__global__ __launch_bounds__(512, 2) void k_argmin(const float* __restrict__ X,
                                                   const float* __restrict__ R,
                                                   const unsigned short* __restrict__ cbh,
                                                   const float* __restrict__ cnorm,
                                                   float* __restrict__ out,
                                                   int* __restrict__ hist) {
    // layout: [0,69632) A-stage overlay (128 tok x 544B) — dead after prologue
    //         [69632,71680) redv[8][64] | [71680,73728) redi[8][64]
    //         [73728,74240) maxvS[128]
    __shared__ __attribute__((aligned(16))) char smem[74240];
    float* redv  = (float*)(smem + 69632);
    int*   redi  = (int*)(smem + 71680);
    float* maxvS = (float*)(smem + 73728);

    const int tid  = threadIdx.x;
    const int w    = tid >> 6;
    const int lane = tid & 63;
    const int lr   = lane & 15;
    const int lq   = lane >> 4;
    const int th   = w >> 2;          // token half
    const int wc   = w & 3;           // code quarter
    const int r0   = blockIdx.x * 128;
    const int mycol = wc * 16 + lr;

    // ---- A-stage: wave w loads tokens [16w,16w+16), row stride 544B ----
    {
        const float4* Xf4 = (const float4*)(X + (size_t)(r0 + 16 * w) * DIM);
        #pragma unroll
        for (int i = 0; i < 16; ++i) {
            const float4 v = Xf4[i * 64 + lane];
            ushort4 u;
            u.x = __builtin_bit_cast(unsigned short, (__bf16)v.x);
            u.y = __builtin_bit_cast(unsigned short, (__bf16)v.y);
            u.z = __builtin_bit_cast(unsigned short, (__bf16)v.z);
            u.w = __builtin_bit_cast(unsigned short, (__bf16)v.w);
            *(ushort4*)(smem + (16 * w + i) * 544 + lane * 8) = u;
        }
    }
    __syncthreads();

    bf16x8 A[4][8];
    #pragma unroll
    for (int mf = 0; mf < 4; ++mf)
        #pragma unroll
        for (int kc = 0; kc < 8; ++kc)
            A[mf][kc] = *(const bf16x8*)(smem + (64 * th + mf * 16 + lr) * 544 + kc * 64 + lq * 16);
    // nothing overwrites the A region during the loop; no barrier needed.

    float maxv[16];
    int   maxi[16];
    #pragma unroll
    for (int i = 0; i < 16; ++i) { maxv[i] = -3.4e38f; maxi[i] = 0; }

    // per-lane B fragment source (fragment-ordered codebook):
    //   chunk cc, kc:  cbh + (cc*4 + wc)*8192 + kc*1024 + lane*16
    const char* bp = (const char*)cbh + (size_t)wc * 8192 + (size_t)lane * 16;

    for (int cc = 0; cc < 128; ++cc) {
        // cn first: oldest outstanding vmem of the iteration, so its wait
        // at the tail never forces the b[] stream to retire.
        const float cn = cnorm[cc * 64 + mycol];

        bf16x8 b[8];
        #pragma unroll
        for (int kc = 0; kc < 8; ++kc)
            b[kc] = *(const bf16x8*)(bp + (size_t)cc * 32768 + kc * 1024);

        f32x4 acc[4];
        #pragma unroll
        for (int mf = 0; mf < 4; ++mf) {
            acc[mf][0] = 0.f; acc[mf][1] = 0.f; acc[mf][2] = 0.f; acc[mf][3] = 0.f;
        }

        #pragma unroll
        for (int kc = 0; kc < 8; ++kc)
            #pragma unroll
            for (int mf = 0; mf < 4; ++mf)
                acc[mf] = __builtin_amdgcn_mfma_f32_16x16x32_bf16(A[mf][kc], b[kc], acc[mf], 0, 0, 0);

        const int col = cc * 64 + mycol;
        #pragma unroll
        for (int mf = 0; mf < 4; ++mf)
            #pragma unroll
            for (int r = 0; r < 4; ++r) {
                const float v = fmaf(-0.5f, cn, acc[mf][r]);
                const int j = mf * 4 + r;
                if (v > maxv[j]) { maxv[j] = v; maxi[j] = col; }
            }
    }

    // ---- reduce across the 16 lanes (lr) sharing each token row ----
    #pragma unroll
    for (int mf = 0; mf < 4; ++mf)
        #pragma unroll
        for (int r = 0; r < 4; ++r) {
            float v = maxv[mf * 4 + r]; int ix = maxi[mf * 4 + r];
            #pragma unroll
            for (int d = 1; d <= 8; d <<= 1) {
                const float ov = __shfl_xor(v, d);
                const int   oi = __shfl_xor(ix, d);
                if (ov > v || (ov == v && oi < ix)) { v = ov; ix = oi; }
            }
            if (lr == 0) {
                const int row = mf * 16 + lq * 4 + r;   // token row within half
                redv[w * 64 + row] = v; redi[w * 64 + row] = ix;
            }
        }
    __syncthreads();

    // ---- combine the 4 code-quarter waves per token; hist + maxvS ----
    if (tid < 128) {
        const int t = tid, tth = t >> 6, tl = t & 63;
        float v = redv[(4 * tth) * 64 + tl]; int ix = redi[(4 * tth) * 64 + tl];
        #pragma unroll
        for (int ww = 1; ww < 4; ++ww) {
            const float ov = redv[(4 * tth + ww) * 64 + tl];
            const int   oi = redi[(4 * tth + ww) * 64 + tl];
            if (ov > v || (ov == v && oi < ix)) { v = ov; ix = oi; }
        }
        maxvS[t] = v;
        atomicAdd(&hist[ix], 1);
    }
    __syncthreads();

    // ---- fused quant epilogue: wave w handles tokens [16w, 16w+16) ----
    for (int i = 0; i < 16; ++i) {
        const int tl = 16 * w + i;
        const int tok = r0 + tl;
        const float4 x = ((const float4*)(X + (size_t)tok * DIM))[lane];
        const float4 r = ((const float4*)(R + (size_t)tok * DIM))[lane];

        float x2 = x.x * x.x + x.y * x.y + x.z * x.z + x.w * x.w;
        float n2 = r.x * r.x + r.y * r.y + r.z * r.z + r.w * r.w;
        #pragma unroll
        for (int d = 1; d < 64; d <<= 1) {
            x2 += __shfl_xor(x2, d);
            n2 += __shfl_xor(n2, d);
        }
        const float mv = maxvS[tl];
        const float d2 = fmaxf(fmaf(-2.f, mv, x2), 0.f);
        const float s = sqrtf(d2) / (sqrtf(n2) + EPSF);

        float4 o;
        o.x = fmaf(s, r.x, x.x);
        o.y = fmaf(s, r.y, x.y);
        o.z = fmaf(s, r.z, x.z);
        o.w = fmaf(s, r.w, x.w);
        ((float4*)(out + (size_t)tok * DIM))[lane] = o;
    }
}

// ---------------------------------------------------------------------------
// K3: perplexity + num_unique from histogram. single block, 1024 thr.
// ---------------------------------------------------------------------------
__global__ __launch_bounds__(1024) void k_stats(const int* __restrict__ hist,
                                                float* __restrict__ outs) {
    float s = 0.f; int u = 0;
    for (int b = threadIdx.x; b < N_CODES; b += 1024) {
        const float c = (float)hist[b];
        if (c > 0.f) ++u;
        const float p = c * (1.f / (float)N_TOKENS);
        s += p * logf(p + EPSF);
    }
    #pragma unroll
    for (int d = 1; d < 64; d <<= 1) {
        s += __shfl_xor(s, d);
        u += __shfl_xor(u, d);
    }
    __shared__ float ss[16];
    __shared__ int   su[16];
    const int w = threadIdx.x >> 6, lane = threadIdx.x & 63;
    if (lane == 0) { ss[w] = s; su[w] = u; }
    __syncthreads();
    if (threadIdx.x == 0) {
        float st = 0.f; int ut = 0;
        #pragma unroll
        for (int i = 0; i < 16; ++i) { st += ss[i]; ut += su[i]; }
        outs[0] = expf(-st);       // perplexity
        outs[1] = (float)ut;       // num_unique_indices
    }
}

// ---------------------------------------------------------------------------
extern "C" void kernel_launch(void* const* d_in, const int* in_sizes, int n_in,
                              void* d_out, int out_size, void* d_ws, size_t ws_size,
                              hipStream_t stream) {
    const float* X = (const float*)d_in[0];  // input_data (32768,256)
    const float* R = (const float*)d_in[1];  // rand       (32768,256)
    const float* C = (const float*)d_in[2];  // codebooks  (8192,256)
    float* out = (float*)d_out;

    char* ws = (char*)d_ws;
    unsigned short* cbh = (unsigned short*)ws;             // fragment-order bf16 codebook
    float* cnorm = (float*)(ws + WS_CNORM_OFF);
    int*   hist  = (int*)(ws + WS_HIST_OFF);

    k_prep  <<<512,            256, 0, stream>>>(C, cbh, cnorm, hist);
    k_argmin<<<N_TOKENS / 128, 512, 0, stream>>>(X, R, cbh, cnorm, out, hist);
    k_stats <<<1, 1024, 0, stream>>>(hist, out + (size_t)N_TOKENS * DIM);
}

// Round 7
// 236.865 us; speedup vs baseline: 1.3106x; 1.3106x over previous
//
#include <hip/hip_runtime.h>
#include <stdint.h>

#define N_TOKENS 32768
#define N_CODES  8192
#define DIM      256
#define EPSF     1e-8f

typedef __bf16 bf16x8 __attribute__((ext_vector_type(8)));
typedef float  f32x4  __attribute__((ext_vector_type(4)));
typedef unsigned short ushort8 __attribute__((ext_vector_type(8)));

// ws layout: [bf16 codebook, FRAGMENT ORDER, 4MiB][cnorm f32 32KiB][hist 32KiB]
#define WS_CNORM_OFF  (4u*1024u*1024u)
#define WS_HIST_OFF   (WS_CNORM_OFF + N_CODES*4u)

// ---------------------------------------------------------------------------
// K1: codebooks fp32 -> bf16 in MFMA-FRAGMENT ORDER, ||c||^2, zero hist.
//  Fragment layout: group g = cc*4 + q (16 codes), within group:
//    byte offset = kc*1024 + lane*16,  lane = lq*16 + lr
//    holds code row (g*16 + lr), dims [kc*32 + lq*8, +8) as 8 bf16.
// ---------------------------------------------------------------------------
__global__ __launch_bounds__(256) void k_prep(const float* __restrict__ cbf,
                                              unsigned short* __restrict__ cbh,
                                              float* __restrict__ cnorm,
                                              int* __restrict__ hist) {
    const int g   = blockIdx.x;        // code group 0..511 (16 codes each)
    const int tid = threadIdx.x;
    if (g < 32) hist[g * 256 + tid] = 0;

    __shared__ float nrm[16];
    if (tid < 16) nrm[tid] = 0.f;
    __syncthreads();

    #pragma unroll
    for (int i = 0; i < 2; ++i) {
        const int e  = i * 256 + tid;          // 0..511
        const int kc = e >> 6;
        const int ln = e & 63;
        const int lq = ln >> 4, lr = ln & 15;
        const float* src = cbf + ((size_t)(g * 16 + lr)) * DIM + kc * 32 + lq * 8;
        const float4 v0 = ((const float4*)src)[0];
        const float4 v1 = ((const float4*)src)[1];

        ushort8 u;
        u[0] = __builtin_bit_cast(unsigned short, (__bf16)v0.x);
        u[1] = __builtin_bit_cast(unsigned short, (__bf16)v0.y);
        u[2] = __builtin_bit_cast(unsigned short, (__bf16)v0.z);
        u[3] = __builtin_bit_cast(unsigned short, (__bf16)v0.w);
        u[4] = __builtin_bit_cast(unsigned short, (__bf16)v1.x);
        u[5] = __builtin_bit_cast(unsigned short, (__bf16)v1.y);
        u[6] = __builtin_bit_cast(unsigned short, (__bf16)v1.z);
        u[7] = __builtin_bit_cast(unsigned short, (__bf16)v1.w);
        *(ushort8*)((char*)cbh + (size_t)g * 8192 + kc * 1024 + ln * 16) = u;

        const float p = v0.x*v0.x + v0.y*v0.y + v0.z*v0.z + v0.w*v0.w
                      + v1.x*v1.x + v1.y*v1.y + v1.z*v1.z + v1.w*v1.w;
        atomicAdd(&nrm[lr], p);
    }
    __syncthreads();
    if (tid < 16) cnorm[g * 16 + tid] = nrm[tid];
}

// ---------------------------------------------------------------------------
// K2: fused distance-matmul + argmax(x.c - cn/2) + quant epilogue, v12.
//  v12 = v11's register-direct B path + EXPLICIT 1-chunk register prefetch.
//  v11 post-mortem: chunk = 4181 cyc, MFMA 1045 + VALU 920 + ~2200 EXPOSED
//  L2 LATENCY -- loads were issued then consumed immediately; the compiler
//  does not software-pipeline loop-carried register loads. Bandwidth was
//  never the wall (B stream ~1.2 TB/s/XCD vs 4.3 ceiling).
//  Fix: double-buffered prefetch with NAMED buffers bA/bB (rule #20: no
//  runtime indexing -> unroll x2). Steady state per iteration:
//    issue loads(cc+1)->bB ; MFMA+tail(bA) ; issue loads(cc+2)->bA ;
//    MFMA+tail(bB).
//  Each batch gets >=600 cyc of MFMA shadow (per-SIMD MFMA phase = 1242
//  cyc/chunk) -- covers contended L2 latency. All loads are plain register
//  loads, so the compiler's exact per-register vmcnt applies (no DMA
//  in-order-retire trap). Main loop: zero LDS, zero barriers.
// ---------------------------------------------------------------------------
__global__ __launch_bounds__(512, 2) void k_argmin(const float* __restrict__ X,
                                                   const float* __restrict__ R,
                                                   const unsigned short* __restrict__ cbh,
                                                   const float* __restrict__ cnorm,
                                                   float* __restrict__ out,
                                                   int* __restrict__ hist) {
    // layout: [0,69632) A-stage overlay (128 tok x 544B) — dead after prologue
    //         [69632,71680) redv[8][64] | [71680,73728) redi[8][64]
    //         [73728,74240) maxvS[128]
    __shared__ __attribute__((aligned(16))) char smem[74240];
    float* redv  = (float*)(smem + 69632);
    int*   redi  = (int*)(smem + 71680);
    float* maxvS = (float*)(smem + 73728);

    const int tid  = threadIdx.x;
    const int w    = tid >> 6;
    const int lane = tid & 63;
    const int lr   = lane & 15;
    const int lq   = lane >> 4;
    const int th   = w >> 2;          // token half
    const int wc   = w & 3;           // code quarter
    const int r0   = blockIdx.x * 128;
    const int mycol = wc * 16 + lr;

    // ---- A-stage: wave w loads tokens [16w,16w+16), row stride 544B ----
    {
        const float4* Xf4 = (const float4*)(X + (size_t)(r0 + 16 * w) * DIM);
        #pragma unroll
        for (int i = 0; i < 16; ++i) {
            const float4 v = Xf4[i * 64 + lane];
            ushort4 u;
            u.x = __builtin_bit_cast(unsigned short, (__bf16)v.x);
            u.y = __builtin_bit_cast(unsigned short, (__bf16)v.y);
            u.z = __builtin_bit_cast(unsigned short, (__bf16)v.z);
            u.w = __builtin_bit_cast(unsigned short, (__bf16)v.w);
            *(ushort4*)(smem + (16 * w + i) * 544 + lane * 8) = u;
        }
    }
    __syncthreads();

    bf16x8 A[4][8];
    #pragma unroll
    for (int mf = 0; mf < 4; ++mf)
        #pragma unroll
        for (int kc = 0; kc < 8; ++kc)
            A[mf][kc] = *(const bf16x8*)(smem + (64 * th + mf * 16 + lr) * 544 + kc * 64 + lq * 16);
    // nothing overwrites the A region during the loop; no barrier needed.

    float maxv[16];
    int   maxi[16];
    #pragma unroll
    for (int i = 0; i < 16; ++i) { maxv[i] = -3.4e38f; maxi[i] = 0; }

    // per-lane B fragment source (fragment-ordered codebook):
    //   chunk cc, kc:  cbh + (cc*4 + wc)*8192 + kc*1024 + lane*16
    const char* bp = (const char*)cbh + (size_t)wc * 8192 + (size_t)lane * 16;
    const float* cnp = cnorm + mycol;

    bf16x8 bA[8], bB[8];
    float cnA, cnB;

    // ---- preload chunk 0 into bA ----
    #pragma unroll
    for (int kc = 0; kc < 8; ++kc)
        bA[kc] = *(const bf16x8*)(bp + kc * 1024);
    cnA = cnp[0];

    for (int cc = 0; cc < 128; cc += 2) {
        // ---- prefetch chunk cc+1 -> bB (always valid: cc <= 126) ----
        {
            const char* s = bp + (size_t)(cc + 1) * 32768;
            #pragma unroll
            for (int kc = 0; kc < 8; ++kc)
                bB[kc] = *(const bf16x8*)(s + kc * 1024);
            cnB = cnp[(cc + 1) * 64];
        }

        // ---- compute chunk cc with bA ----
        {
            f32x4 acc[4];
            #pragma unroll
            for (int mf = 0; mf < 4; ++mf) {
                acc[mf][0] = 0.f; acc[mf][1] = 0.f; acc[mf][2] = 0.f; acc[mf][3] = 0.f;
            }
            #pragma unroll
            for (int kc = 0; kc < 8; ++kc)
                #pragma unroll
                for (int mf = 0; mf < 4; ++mf)
                    acc[mf] = __builtin_amdgcn_mfma_f32_16x16x32_bf16(A[mf][kc], bA[kc], acc[mf], 0, 0, 0);

            const int col = cc * 64 + mycol;
            #pragma unroll
            for (int mf = 0; mf < 4; ++mf)
                #pragma unroll
                for (int r = 0; r < 4; ++r) {
                    const float v = fmaf(-0.5f, cnA, acc[mf][r]);
                    const int j = mf * 4 + r;
                    if (v > maxv[j]) { maxv[j] = v; maxi[j] = col; }
                }
        }

        // ---- prefetch chunk cc+2 -> bA ----
        if (cc + 2 < 128) {
            const char* s = bp + (size_t)(cc + 2) * 32768;
            #pragma unroll
            for (int kc = 0; kc < 8; ++kc)
                bA[kc] = *(const bf16x8*)(s + kc * 1024);
            cnA = cnp[(cc + 2) * 64];
        }

        // ---- compute chunk cc+1 with bB ----
        {
            f32x4 acc[4];
            #pragma unroll
            for (int mf = 0; mf < 4; ++mf) {
                acc[mf][0] = 0.f; acc[mf][1] = 0.f; acc[mf][2] = 0.f; acc[mf][3] = 0.f;
            }
            #pragma unroll
            for (int kc = 0; kc < 8; ++kc)
                #pragma unroll
                for (int mf = 0; mf < 4; ++mf)
                    acc[mf] = __builtin_amdgcn_mfma_f32_16x16x32_bf16(A[mf][kc], bB[kc], acc[mf], 0, 0, 0);

            const int col = (cc + 1) * 64 + mycol;
            #pragma unroll
            for (int mf = 0; mf < 4; ++mf)
                #pragma unroll
                for (int r = 0; r < 4; ++r) {
                    const float v = fmaf(-0.5f, cnB, acc[mf][r]);
                    const int j = mf * 4 + r;
                    if (v > maxv[j]) { maxv[j] = v; maxi[j] = col; }
                }
        }
    }

    // ---- reduce across the 16 lanes (lr) sharing each token row ----
    #pragma unroll
    for (int mf = 0; mf < 4; ++mf)
        #pragma unroll
        for (int r = 0; r < 4; ++r) {
            float v = maxv[mf * 4 + r]; int ix = maxi[mf * 4 + r];
            #pragma unroll
            for (int d = 1; d <= 8; d <<= 1) {
                const float ov = __shfl_xor(v, d);
                const int   oi = __shfl_xor(ix, d);
                if (ov > v || (ov == v && oi < ix)) { v = ov; ix = oi; }
            }
            if (lr == 0) {
                const int row = mf * 16 + lq * 4 + r;   // token row within half
                redv[w * 64 + row] = v; redi[w * 64 + row] = ix;
            }
        }
    __syncthreads();

    // ---- combine the 4 code-quarter waves per token; hist + maxvS ----
    if (tid < 128) {
        const int t = tid, tth = t >> 6, tl = t & 63;
        float v = redv[(4 * tth) * 64 + tl]; int ix = redi[(4 * tth) * 64 + tl];
        #pragma unroll
        for (int ww = 1; ww < 4; ++ww) {
            const float ov = redv[(4 * tth + ww) * 64 + tl];
            const int   oi = redi[(4 * tth + ww) * 64 + tl];
            if (ov > v || (ov == v && oi < ix)) { v = ov; ix = oi; }
        }
        maxvS[t] = v;
        atomicAdd(&hist[ix], 1);
    }
    __syncthreads();

    // ---- fused quant epilogue: wave w handles tokens [16w, 16w+16) ----
    for (int i = 0; i < 16; ++i) {
        const int tl = 16 * w + i;
        const int tok = r0 + tl;
        const float4 x = ((const float4*)(X + (size_t)tok * DIM))[lane];
        const float4 r = ((const float4*)(R + (size_t)tok * DIM))[lane];

        float x2 = x.x * x.x + x.y * x.y + x.z * x.z + x.w * x.w;
        float n2 = r.x * r.x + r.y * r.y + r.z * r.z + r.w * r.w;
        #pragma unroll
        for (int d = 1; d < 64; d <<= 1) {
            x2 += __shfl_xor(x2, d);
            n2 += __shfl_xor(n2, d);
        }
        const float mv = maxvS[tl];
        const float d2 = fmaxf(fmaf(-2.f, mv, x2), 0.f);
        const float s = sqrtf(d2) / (sqrtf(n2) + EPSF);

        float4 o;
        o.x = fmaf(s, r.x, x.x);
        o.y = fmaf(s, r.y, x.y);
        o.z = fmaf(s, r.z, x.z);
        o.w = fmaf(s, r.w, x.w);
        ((float4*)(out + (size_t)tok * DIM))[lane] = o;
    }
}

// ---------------------------------------------------------------------------
// K3: perplexity + num_unique from histogram. single block, 1024 thr.
// ---------------------------------------------------------------------------
__global__ __launch_bounds__(1024) void k_stats(const int* __restrict__ hist,
                                                float* __restrict__ outs) {
    float s = 0.f; int u = 0;
    for (int b = threadIdx.x; b < N_CODES; b += 1024) {
        const float c = (float)hist[b];
        if (c > 0.f) ++u;
        const float p = c * (1.f / (float)N_TOKENS);
        s += p * logf(p + EPSF);
    }
    #pragma unroll
    for (int d = 1; d < 64; d <<= 1) {
        s += __shfl_xor(s, d);
        u += __shfl_xor(u, d);
    }
    __shared__ float ss[16];
    __shared__ int   su[16];
    const int w = threadIdx.x >> 6, lane = threadIdx.x & 63;
    if (lane == 0) { ss[w] = s; su[w] = u; }
    __syncthreads();
    if (threadIdx.x == 0) {
        float st = 0.f; int ut = 0;
        #pragma unroll
        for (int i = 0; i < 16; ++i) { st += ss[i]; ut += su[i]; }
        outs[0] = expf(-st);       // perplexity
        outs[1] = (float)ut;       // num_unique_indices
    }
}

// ---------------------------------------------------------------------------
extern "C" void kernel_launch(void* const* d_in, const int* in_sizes, int n_in,
                              void* d_out, int out_size, void* d_ws, size_t ws_size,
                              hipStream_t stream) {
    const float* X = (const float*)d_in[0];  // input_data (32768,256)
    const float* R = (const float*)d_in[1];  // rand       (32768,256)
    const float* C = (const float*)d_in[2];  // codebooks  (8192,256)
    float* out = (float*)d_out;

    char* ws = (char*)d_ws;
    unsigned short* cbh = (unsigned short*)ws;             // fragment-order bf16 codebook
    float* cnorm = (float*)(ws + WS_CNORM_OFF);
    int*   hist  = (int*)(ws + WS_HIST_OFF);

    k_prep  <<<512,            256, 0, stream>>>(C, cbh, cnorm, hist);
    k_argmin<<<N_TOKENS / 128, 512, 0, stream>>>(X, R, cbh, cnorm, out, hist);
    k_stats <<<1, 1024, 0, stream>>>(hist, out + (size_t)N_TOKENS * DIM);
}

// Round 8
// 234.632 us; speedup vs baseline: 1.3230x; 1.0095x over previous
//
#include <hip/hip_runtime.h>
#include <stdint.h>

#define N_TOKENS 32768
#define N_CODES  8192
#define DIM      256
#define EPSF     1e-8f

typedef __bf16 bf16x8 __attribute__((ext_vector_type(8)));
typedef float  f32x4  __attribute__((ext_vector_type(4)));
typedef unsigned short ushort8 __attribute__((ext_vector_type(8)));

// ws layout: [bf16 codebook, FRAGMENT ORDER, 4MiB][cnorm f32 32KiB][hist 32KiB]
#define WS_CNORM_OFF  (4u*1024u*1024u)
#define WS_HIST_OFF   (WS_CNORM_OFF + N_CODES*4u)

// ---------------------------------------------------------------------------
// K1: codebooks fp32 -> bf16 in MFMA-FRAGMENT ORDER, ||c||^2, zero hist.
//  Fragment layout: group g = cc*4 + q (16 codes), within group:
//    byte offset = kc*1024 + lane*16,  lane = lq*16 + lr
//    holds code row (g*16 + lr), dims [kc*32 + lq*8, +8) as 8 bf16.
// ---------------------------------------------------------------------------
__global__ __launch_bounds__(256) void k_prep(const float* __restrict__ cbf,
                                              unsigned short* __restrict__ cbh,
                                              float* __restrict__ cnorm,
                                              int* __restrict__ hist) {
    const int g   = blockIdx.x;        // code group 0..511 (16 codes each)
    const int tid = threadIdx.x;
    if (g < 32) hist[g * 256 + tid] = 0;

    __shared__ float nrm[16];
    if (tid < 16) nrm[tid] = 0.f;
    __syncthreads();

    #pragma unroll
    for (int i = 0; i < 2; ++i) {
        const int e  = i * 256 + tid;          // 0..511
        const int kc = e >> 6;
        const int ln = e & 63;
        const int lq = ln >> 4, lr = ln & 15;
        const float* src = cbf + ((size_t)(g * 16 + lr)) * DIM + kc * 32 + lq * 8;
        const float4 v0 = ((const float4*)src)[0];
        const float4 v1 = ((const float4*)src)[1];

        ushort8 u;
        u[0] = __builtin_bit_cast(unsigned short, (__bf16)v0.x);
        u[1] = __builtin_bit_cast(unsigned short, (__bf16)v0.y);
        u[2] = __builtin_bit_cast(unsigned short, (__bf16)v0.z);
        u[3] = __builtin_bit_cast(unsigned short, (__bf16)v0.w);
        u[4] = __builtin_bit_cast(unsigned short, (__bf16)v1.x);
        u[5] = __builtin_bit_cast(unsigned short, (__bf16)v1.y);
        u[6] = __builtin_bit_cast(unsigned short, (__bf16)v1.z);
        u[7] = __builtin_bit_cast(unsigned short, (__bf16)v1.w);
        *(ushort8*)((char*)cbh + (size_t)g * 8192 + kc * 1024 + ln * 16) = u;

        const float p = v0.x*v0.x + v0.y*v0.y + v0.z*v0.z + v0.w*v0.w
                      + v1.x*v1.x + v1.y*v1.y + v1.z*v1.z + v1.w*v1.w;
        atomicAdd(&nrm[lr], p);
    }
    __syncthreads();
    if (tid < 16) cnorm[g * 16 + tid] = nrm[tid];
}

// ---------------------------------------------------------------------------
// K2: fused distance-matmul + argmax(x.c - cn/2) + quant epilogue, v13.
//  v13 = v12 (register-direct fragment-ordered B, depth-1 prefetch) with the
//  vmem pipeline taken AWAY from the compiler (T4 counted-vmcnt, HK-style):
//   - All loop vmem is inline-asm: per chunk ONE 9-op group
//     (8x global_load_dwordx4 B-frags + 1x global_load_dword cn),
//     SGPR base (uniform chunk pointer) + per-lane 32-bit voffset.
//   - Steady state: exactly 2 groups (18 ops) outstanding. `s_waitcnt
//     vmcnt(9)` retires precisely the group about to be consumed, keeping
//     the prefetched group in flight. vmcnt(0) only at the last chunk.
//   - sched_barrier(0) after every wait (rule #18: MFMAs hoist past asm
//     waits otherwise). Volatile-asm ordering pins issue(cc+2) AFTER
//     compute(cc) -> guaranteed >=1 compute phase (~1200+cyc) of shadow;
//     the compiler can no longer sink loads to their uses (its pressure
//     heuristic defeated v12's intended distance: 42% MfmaUtil, ~1000cyc
//     exposed latency per chunk).
//  Main loop: zero LDS, zero barriers, zero compiler vmem.
// ---------------------------------------------------------------------------
__global__ __launch_bounds__(512, 2) void k_argmin(const float* __restrict__ X,
                                                   const float* __restrict__ R,
                                                   const unsigned short* __restrict__ cbh,
                                                   const float* __restrict__ cnorm,
                                                   float* __restrict__ out,
                                                   int* __restrict__ hist) {
    // layout: [0,69632) A-stage overlay (128 tok x 544B) — dead after prologue
    //         [69632,71680) redv[8][64] | [71680,73728) redi[8][64]
    //         [73728,74240) maxvS[128]
    __shared__ __attribute__((aligned(16))) char smem[74240];
    float* redv  = (float*)(smem + 69632);
    int*   redi  = (int*)(smem + 71680);
    float* maxvS = (float*)(smem + 73728);

    const int tid  = threadIdx.x;
    const int w    = tid >> 6;
    const int lane = tid & 63;
    const int lr   = lane & 15;
    const int lq   = lane >> 4;
    const int th   = w >> 2;          // token half
    const int wc   = w & 3;           // code quarter
    const int r0   = blockIdx.x * 128;
    const int mycol = wc * 16 + lr;

    // ---- A-stage: wave w loads tokens [16w,16w+16), row stride 544B ----
    {
        const float4* Xf4 = (const float4*)(X + (size_t)(r0 + 16 * w) * DIM);
        #pragma unroll
        for (int i = 0; i < 16; ++i) {
            const float4 v = Xf4[i * 64 + lane];
            ushort4 u;
            u.x = __builtin_bit_cast(unsigned short, (__bf16)v.x);
            u.y = __builtin_bit_cast(unsigned short, (__bf16)v.y);
            u.z = __builtin_bit_cast(unsigned short, (__bf16)v.z);
            u.w = __builtin_bit_cast(unsigned short, (__bf16)v.w);
            *(ushort4*)(smem + (16 * w + i) * 544 + lane * 8) = u;
        }
    }
    __syncthreads();

    bf16x8 A[4][8];
    #pragma unroll
    for (int mf = 0; mf < 4; ++mf)
        #pragma unroll
        for (int kc = 0; kc < 8; ++kc)
            A[mf][kc] = *(const bf16x8*)(smem + (64 * th + mf * 16 + lr) * 544 + kc * 64 + lq * 16);
    // nothing overwrites the A region during the loop; no barrier needed.
    // (compiler waits vmcnt(0)+lgkmcnt(0) at the __syncthreads above, so at
    //  loop entry the ONLY outstanding vmem is what we issue below.)

    float maxv[16];
    int   maxi[16];
    #pragma unroll
    for (int i = 0; i < 16; ++i) { maxv[i] = -3.4e38f; maxi[i] = 0; }

    // per-lane voffsets for the fragment-ordered codebook:
    //   group base (SGPR) = cbh + chunk*32768 ; voff = wc*8192 + lane*16
    const unsigned int voff  = (unsigned int)(wc * 8192 + lane * 16);
    const unsigned int voff2 = voff + 4096u;
    const unsigned int voffc = (unsigned int)(mycol * 4);

    bf16x8 bA[8], bB[8];
    float cnA, cnB;

#define ISSUE_GRP(buf, cnv, chunk) do {                                               \
    const unsigned short* gb_ = (const unsigned short*)((const char*)cbh +            \
                                                        (size_t)(chunk) * 32768);    \
    const float* cb_ = cnorm + (size_t)(chunk) * 64;                                  \
    asm volatile("global_load_dwordx4 %0, %1, %2"             : "=v"(buf[0]) : "v"(voff),  "s"(gb_)); \
    asm volatile("global_load_dwordx4 %0, %1, %2 offset:1024" : "=v"(buf[1]) : "v"(voff),  "s"(gb_)); \
    asm volatile("global_load_dwordx4 %0, %1, %2 offset:2048" : "=v"(buf[2]) : "v"(voff),  "s"(gb_)); \
    asm volatile("global_load_dwordx4 %0, %1, %2 offset:3072" : "=v"(buf[3]) : "v"(voff),  "s"(gb_)); \
    asm volatile("global_load_dwordx4 %0, %1, %2"             : "=v"(buf[4]) : "v"(voff2), "s"(gb_)); \
    asm volatile("global_load_dwordx4 %0, %1, %2 offset:1024" : "=v"(buf[5]) : "v"(voff2), "s"(gb_)); \
    asm volatile("global_load_dwordx4 %0, %1, %2 offset:2048" : "=v"(buf[6]) : "v"(voff2), "s"(gb_)); \
    asm volatile("global_load_dwordx4 %0, %1, %2 offset:3072" : "=v"(buf[7]) : "v"(voff2), "s"(gb_)); \
    asm volatile("global_load_dword %0, %1, %2"               : "=v"(cnv)    : "v"(voffc), "s"(cb_)); \
} while (0)

#define WAITV9 do { asm volatile("s_waitcnt vmcnt(9)" ::: "memory");                  \
                    __builtin_amdgcn_sched_barrier(0); } while (0)
#define WAITV0 do { asm volatile("s_waitcnt vmcnt(0)" ::: "memory");                  \
                    __builtin_amdgcn_sched_barrier(0); } while (0)

#define COMPUTE_CHUNK(chunk, buf, cnv) do {                                           \
    f32x4 acc_[4];                                                                    \
    _Pragma("unroll") for (int mf_ = 0; mf_ < 4; ++mf_) {                             \
        acc_[mf_][0] = 0.f; acc_[mf_][1] = 0.f; acc_[mf_][2] = 0.f; acc_[mf_][3] = 0.f; } \
    _Pragma("unroll") for (int kc_ = 0; kc_ < 8; ++kc_)                               \
        _Pragma("unroll") for (int mf_ = 0; mf_ < 4; ++mf_)                           \
            acc_[mf_] = __builtin_amdgcn_mfma_f32_16x16x32_bf16(A[mf_][kc_], buf[kc_],\
                                                                acc_[mf_], 0, 0, 0);  \
    const int col_ = (chunk) * 64 + mycol;                                            \
    _Pragma("unroll") for (int mf_ = 0; mf_ < 4; ++mf_)                               \
        _Pragma("unroll") for (int r_ = 0; r_ < 4; ++r_) {                            \
            const float v_ = fmaf(-0.5f, (cnv), acc_[mf_][r_]);                       \
            const int j_ = mf_ * 4 + r_;                                              \
            if (v_ > maxv[j_]) { maxv[j_] = v_; maxi[j_] = col_; }                    \
        }                                                                             \
} while (0)

    // ---- prologue: 2 groups in flight ----
    ISSUE_GRP(bA, cnA, 0);
    ISSUE_GRP(bB, cnB, 1);

    // ---- steady state: always 2 groups outstanding; waits count, never drain
    for (int cc = 0; cc < 126; cc += 2) {
        WAITV9;                               // retire group cc (oldest 9)
        COMPUTE_CHUNK(cc, bA, cnA);
        ISSUE_GRP(bA, cnA, cc + 2);
        WAITV9;                               // retire group cc+1
        COMPUTE_CHUNK(cc + 1, bB, cnB);
        ISSUE_GRP(bB, cnB, cc + 3);
    }
    WAITV9;                                   // retire group 126
    COMPUTE_CHUNK(126, bA, cnA);
    WAITV0;                                   // retire group 127
    COMPUTE_CHUNK(127, bB, cnB);

#undef ISSUE_GRP
#undef WAITV9
#undef WAITV0
#undef COMPUTE_CHUNK

    // ---- reduce across the 16 lanes (lr) sharing each token row ----
    #pragma unroll
    for (int mf = 0; mf < 4; ++mf)
        #pragma unroll
        for (int r = 0; r < 4; ++r) {
            float v = maxv[mf * 4 + r]; int ix = maxi[mf * 4 + r];
            #pragma unroll
            for (int d = 1; d <= 8; d <<= 1) {
                const float ov = __shfl_xor(v, d);
                const int   oi = __shfl_xor(ix, d);
                if (ov > v || (ov == v && oi < ix)) { v = ov; ix = oi; }
            }
            if (lr == 0) {
                const int row = mf * 16 + lq * 4 + r;   // token row within half
                redv[w * 64 + row] = v; redi[w * 64 + row] = ix;
            }
        }
    __syncthreads();

    // ---- combine the 4 code-quarter waves per token; hist + maxvS ----
    if (tid < 128) {
        const int t = tid, tth = t >> 6, tl = t & 63;
        float v = redv[(4 * tth) * 64 + tl]; int ix = redi[(4 * tth) * 64 + tl];
        #pragma unroll
        for (int ww = 1; ww < 4; ++ww) {
            const float ov = redv[(4 * tth + ww) * 64 + tl];
            const int   oi = redi[(4 * tth + ww) * 64 + tl];
            if (ov > v || (ov == v && oi < ix)) { v = ov; ix = oi; }
        }
        maxvS[t] = v;
        atomicAdd(&hist[ix], 1);
    }
    __syncthreads();

    // ---- fused quant epilogue: wave w handles tokens [16w, 16w+16) ----
    for (int i = 0; i < 16; ++i) {
        const int tl = 16 * w + i;
        const int tok = r0 + tl;
        const float4 x = ((const float4*)(X + (size_t)tok * DIM))[lane];
        const float4 r = ((const float4*)(R + (size_t)tok * DIM))[lane];

        float x2 = x.x * x.x + x.y * x.y + x.z * x.z + x.w * x.w;
        float n2 = r.x * r.x + r.y * r.y + r.z * r.z + r.w * r.w;
        #pragma unroll
        for (int d = 1; d < 64; d <<= 1) {
            x2 += __shfl_xor(x2, d);
            n2 += __shfl_xor(n2, d);
        }
        const float mv = maxvS[tl];
        const float d2 = fmaxf(fmaf(-2.f, mv, x2), 0.f);
        const float s = sqrtf(d2) / (sqrtf(n2) + EPSF);

        float4 o;
        o.x = fmaf(s, r.x, x.x);
        o.y = fmaf(s, r.y, x.y);
        o.z = fmaf(s, r.z, x.z);
        o.w = fmaf(s, r.w, x.w);
        ((float4*)(out + (size_t)tok * DIM))[lane] = o;
    }
}

// ---------------------------------------------------------------------------
// K3: perplexity + num_unique from histogram. single block, 1024 thr.
// ---------------------------------------------------------------------------
__global__ __launch_bounds__(1024) void k_stats(const int* __restrict__ hist,
                                                float* __restrict__ outs) {
    float s = 0.f; int u = 0;
    for (int b = threadIdx.x; b < N_CODES; b += 1024) {
        const float c = (float)hist[b];
        if (c > 0.f) ++u;
        const float p = c * (1.f / (float)N_TOKENS);
        s += p * logf(p + EPSF);
    }
    #pragma unroll
    for (int d = 1; d < 64; d <<= 1) {
        s += __shfl_xor(s, d);
        u += __shfl_xor(u, d);
    }
    __shared__ float ss[16];
    __shared__ int   su[16];
    const int w = threadIdx.x >> 6, lane = threadIdx.x & 63;
    if (lane == 0) { ss[w] = s; su[w] = u; }
    __syncthreads();
    if (threadIdx.x == 0) {
        float st = 0.f; int ut = 0;
        #pragma unroll
        for (int i = 0; i < 16; ++i) { st += ss[i]; ut += su[i]; }
        outs[0] = expf(-st);       // perplexity
        outs[1] = (float)ut;       // num_unique_indices
    }
}

// ---------------------------------------------------------------------------
extern "C" void kernel_launch(void* const* d_in, const int* in_sizes, int n_in,
                              void* d_out, int out_size, void* d_ws, size_t ws_size,
                              hipStream_t stream) {
    const float* X = (const float*)d_in[0];  // input_data (32768,256)
    const float* R = (const float*)d_in[1];  // rand       (32768,256)
    const float* C = (const float*)d_in[2];  // codebooks  (8192,256)
    float* out = (float*)d_out;

    char* ws = (char*)d_ws;
    unsigned short* cbh = (unsigned short*)ws;             // fragment-order bf16 codebook
    float* cnorm = (float*)(ws + WS_CNORM_OFF);
    int*   hist  = (int*)(ws + WS_HIST_OFF);

    k_prep  <<<512,            256, 0, stream>>>(C, cbh, cnorm, hist);
    k_argmin<<<N_TOKENS / 128, 512, 0, stream>>>(X, R, cbh, cnorm, out, hist);
    k_stats <<<1, 1024, 0, stream>>>(hist, out + (size_t)N_TOKENS * DIM);
}